// Round 10
// baseline (111.615 us; speedup 1.0000x reference)
//
#include <hip/hip_runtime.h>
#include <hip/hip_bf16.h>

typedef __attribute__((ext_vector_type(8))) short bf16x8;
typedef __attribute__((ext_vector_type(4))) float f32x4;

#define NCOLP 384                 // padded columns (352 real + 32 zero)
#define STEP_SHORTS (NCOLP * 32)  // 12288 shorts = 24576 B per 32-k step
#define STEP_BYTES 24576
#define SEG_BYTES 6144            // Wpack per-ablk segment: 384 cols * 8k * 2B
#define NSTEP 32
#define BROWS 65536
#define A_SLOT 8192               // 64 rows * 128 B fp32 per k-step slot

static __device__ __forceinline__ unsigned int bf16rne(float f) {
  unsigned int u = __float_as_uint(f);
  return (u + 0x7FFFu + ((u >> 16) & 1u)) >> 16;
}
static __device__ __forceinline__ unsigned int pack2(float a, float b) {
  return bf16rne(a) | (bf16rne(b) << 16);
}
static __device__ __forceinline__ void gload16(const void* g, void* l) {
  __builtin_amdgcn_global_load_lds(
      (const __attribute__((address_space(1))) unsigned int*)g,
      (__attribute__((address_space(3))) unsigned int*)l, 16, 0, 0);
}

// Wpack layout: [step][ablk(4)][col(384)][k%8] (bf16), 24576 B/step.
// Column map: [0,100) task0 (e*10+h), [100,200) task1, [200,300) shared,
// [300,340) gates (t*20+g), [340,384) zero pad.
__global__ void ple_prep(const float* __restrict__ Ws, const float* __restrict__ bs,
                         const float* __restrict__ Wt, const float* __restrict__ bt,
                         const float* __restrict__ Wg, const float* __restrict__ bg,
                         unsigned short* __restrict__ Wpack, float* __restrict__ bias) {
  const int n = blockIdx.x;  // 0..383
  const int tid = threadIdx.x;
  const float* src = nullptr;
  int stride = 0;
  float bval = 0.f;
  if (n < 200) {
    int t = n / 100, m = n % 100, e = m / 10, h = m % 10;
    src = Wt + (size_t)(t * 10 + e) * 10240 + h;
    stride = 10;
    bval = bt[(t * 10 + e) * 10 + h];
  } else if (n < 300) {
    int m = n - 200, e = m / 10, h = m % 10;
    src = Ws + (size_t)e * 10240 + h;
    stride = 10;
    bval = bs[e * 10 + h];
  } else if (n < 340) {
    int m = n - 300, t = m / 20, g = m % 20;
    src = Wg + (size_t)t * 20480 + g;
    stride = 20;
    bval = bg[t * 20 + g];
  }
  for (int j = 0; j < 4; j++) {
    int k = tid + j * 256;
    float v = src ? src[(size_t)k * stride] : 0.f;
    Wpack[(size_t)(k >> 5) * STEP_SHORTS + ((k >> 3) & 3) * (NCOLP * 8) + n * 8 +
          (k & 7)] = (unsigned short)bf16rne(v);
  }
  if (tid == 0 && n < 352) bias[n] = bval;
}

// Main: 256 threads = 4 waves, 64 rows/block, 1024 blocks.
// Each wave computes ALL 64 rows (4 m-frags) x its own 96-col slice:
//   - B: 6x16B register loads/iter straight from L2-resident Wpack
//     (no LDS, no duplication), double-banked.
//   - A: global_load_lds once per block into a 4-slot LDS ring, lead 2,
//     XOR source swizzle -> conflict-free ds_read_b128 frags.
// Per-iter: [vmcnt(8) forces only 2-iter-old A][4-wave barrier]
//           [B(j+1)][stage A(j+2)][compute]. No young-load drains.
__global__ __launch_bounds__(256, 2) void ple_main(
    const float* __restrict__ x, const unsigned short* __restrict__ Wpack,
    const float* __restrict__ bias, const float* __restrict__ Wc,
    const float* __restrict__ bc, const float* __restrict__ Wv,
    const float* __restrict__ bv, float* __restrict__ out) {
  __shared__ __align__(16) char smem[45696];  // ring 4*8192=32768; z[32][357] aliases
  float* z = (float*)smem;

  const int tid = threadIdx.x;
  const int l = tid & 63, w = tid >> 6;  // wave w -> cols [w*96, w*96+96)
  const int arow = l & 15, ablk = l >> 4;
  const int rowbase = blockIdx.x * 64;

  const f32x4 fzero = {0.f, 0.f, 0.f, 0.f};
  f32x4 acc[4][6];
#pragma unroll
  for (int i = 0; i < 4; ++i)
#pragma unroll
    for (int j = 0; j < 6; ++j) acc[i][j] = fzero;

  // ---- A staging: 2 chunks per thread (512 x 16B per 8KB slot) ----
  // chunk c: row=c>>3, phys col p=c&7 holds logical k-seg p^(row&7).
  const int c0 = tid, c1 = tid + 256;
  const int r0 = c0 >> 3, r1 = c1 >> 3;
  const int s0 = (c0 & 7) ^ (r0 & 7), s1 = (c1 & 7) ^ (r1 & 7);
  const char* asrc0 = (const char*)x + (size_t)(rowbase + r0) * 4096 + s0 * 16;
  const char* asrc1 = (const char*)x + (size_t)(rowbase + r1) * 4096 + s1 * 16;
  char* adst0 = smem + c0 * 16;  // + slot*A_SLOT
  char* adst1 = smem + c1 * 16;

  // ---- A fragment read offsets (per mf: 2x swizzled ds_read_b128) ----
  const int sp0 = ((ablk * 2) ^ (arow & 7)) * 16;
  const int sp1 = ((ablk * 2 + 1) ^ (arow & 7)) * 16;

  // ---- B fragment base: per-lane 16B from Wpack ----
  const char* bbase = (const char*)Wpack + ablk * SEG_BYTES +
                      (w * 96 + arow) * 16;

  bf16x8 bA[6], bB[6];  // named banks, static indexing only

  // ---- prologue: A(0)->slot0, A(1)->slot1, B(0)->bA ----
  gload16(asrc0, adst0);
  gload16(asrc1, adst1);
  __builtin_amdgcn_sched_barrier(0);
  gload16(asrc0 + 128, adst0 + A_SLOT);
  gload16(asrc1 + 128, adst1 + A_SLOT);
  __builtin_amdgcn_sched_barrier(0);
#pragma unroll
  for (int nt = 0; nt < 6; nt++)
    bA[nt] = *(const bf16x8*)(bbase + nt * 256);
  __builtin_amdgcn_sched_barrier(0);

  // At iter J top: outstanding = [A(J)x2, B(J)x6, A(J+1)x2] = 10.
  // vmcnt(8) forces exactly A(J) (2-iter-old HBM). B(J) consume inside
  // compute waits vmcnt(10) -> keeps all younger loads in flight.
#define ITER(J, SLOT, SSLOT, bc_, bn_)                                         \
  {                                                                            \
    asm volatile("s_waitcnt vmcnt(8)" ::: "memory");                           \
    __builtin_amdgcn_s_barrier();                                              \
    __builtin_amdgcn_sched_barrier(0);                                         \
    const int tB = ((J) + 1 < NSTEP) ? (J) + 1 : NSTEP - 1;                    \
    const char* bp = bbase + (size_t)tB * STEP_BYTES;                          \
    _Pragma("unroll") for (int nt = 0; nt < 6; nt++)                           \
        bn_[nt] = *(const bf16x8*)(bp + nt * 256);                             \
    __builtin_amdgcn_sched_barrier(0);                                         \
    const int tA = ((J) + 2 < NSTEP) ? (J) + 2 : NSTEP - 1;                    \
    gload16(asrc0 + (size_t)tA * 128, adst0 + (SSLOT)*A_SLOT);                 \
    gload16(asrc1 + (size_t)tA * 128, adst1 + (SSLOT)*A_SLOT);                 \
    __builtin_amdgcn_sched_barrier(0);                                         \
    const char* ab = smem + (SLOT)*A_SLOT;                                     \
    _Pragma("unroll") for (int mf = 0; mf < 4; mf++) {                         \
      float4 fa = *(const float4*)(ab + (mf * 16 + arow) * 128 + sp0);         \
      float4 fb = *(const float4*)(ab + (mf * 16 + arow) * 128 + sp1);         \
      union { bf16x8 v; uint4 u; } A;                                          \
      A.u = make_uint4(pack2(fa.x, fa.y), pack2(fa.z, fa.w),                   \
                       pack2(fb.x, fb.y), pack2(fb.z, fb.w));                  \
      _Pragma("unroll") for (int nt = 0; nt < 6; nt++)                         \
          acc[mf][nt] = __builtin_amdgcn_mfma_f32_16x16x32_bf16(               \
              A.v, bc_[nt], acc[mf][nt], 0, 0, 0);                             \
    }                                                                          \
  }

  for (int kk = 0; kk < NSTEP / 4; kk++) {
    ITER(4 * kk + 0, 0, 2, bA, bB)
    ITER(4 * kk + 1, 1, 3, bB, bA)
    ITER(4 * kk + 2, 2, 0, bA, bB)
    ITER(4 * kk + 3, 3, 1, bB, bA)
  }
#undef ITER

  // Full drain (tail re-stages) before z aliases the ring.
  asm volatile("s_waitcnt vmcnt(0)" ::: "memory");
  __syncthreads();

  // ---- epilogue: 2 phases of 32 rows. D layout: row=(l>>4)*4+reg, col=l&15.
#pragma unroll
  for (int p = 0; p < 2; p++) {
    __syncthreads();
#pragma unroll
    for (int q = 0; q < 2; q++) {
      const int mf = p * 2 + q;
#pragma unroll
      for (int nt = 0; nt < 6; nt++) {
        if (w == 3 && nt >= 4) continue;  // cols >= 352 are zero pad
#pragma unroll
        for (int r = 0; r < 4; r++)
          z[(q * 16 + ablk * 4 + r) * 357 + w * 96 + nt * 16 + arow] =
              acc[mf][nt][r];
      }
    }
    __syncthreads();
    if (tid < 64) {
      const int t = tid >> 5, r = tid & 31;
      const float* zr = &z[r * 357];
      float gl[20], m = -1e30f;
#pragma unroll
      for (int u = 0; u < 20; u++) {
        gl[u] = zr[300 + t * 20 + u] + bias[300 + t * 20 + u];
        m = fmaxf(m, gl[u]);
      }
      float pr[20], s = 0.f;
#pragma unroll
      for (int u = 0; u < 20; u++) {
        pr[u] = __expf(gl[u] - m);
        s += pr[u];
      }
      const float inv = 1.f / s;
      const float* Wl = t ? Wv : Wc;
      float wl[10];
#pragma unroll
      for (int h = 0; h < 10; h++) wl[h] = Wl[h];
      float accum = 0.f;
#pragma unroll
      for (int u = 0; u < 10; u++) {
        float d = 0.f;
#pragma unroll
        for (int h = 0; h < 10; h++) {
          int c = t * 100 + u * 10 + h;
          d += fmaxf(zr[c] + bias[c], 0.f) * wl[h];
        }
        accum += pr[u] * d;
      }
#pragma unroll
      for (int u = 0; u < 10; u++) {
        float d = 0.f;
#pragma unroll
        for (int h = 0; h < 10; h++) {
          int c = 200 + u * 10 + h;
          d += fmaxf(zr[c] + bias[c], 0.f) * wl[h];
        }
        accum += pr[10 + u] * d;
      }
      float logit = (t ? bv[0] : bc[0]) + accum * inv;
      out[(size_t)t * BROWS + rowbase + p * 32 + r] =
          1.f / (1.f + __expf(-logit));
    }
  }
}

extern "C" void kernel_launch(void* const* d_in, const int* in_sizes, int n_in,
                              void* d_out, int out_size, void* d_ws, size_t ws_size,
                              hipStream_t stream) {
  const float* x = (const float*)d_in[0];
  const float* Ws = (const float*)d_in[3];
  const float* bs = (const float*)d_in[4];
  const float* Wt = (const float*)d_in[5];
  const float* bt = (const float*)d_in[6];
  const float* Wg = (const float*)d_in[7];
  const float* bg = (const float*)d_in[8];
  const float* Wc = (const float*)d_in[9];
  const float* bc = (const float*)d_in[10];
  const float* Wv = (const float*)d_in[11];
  const float* bv = (const float*)d_in[12];
  unsigned short* Wpack = (unsigned short*)d_ws;
  float* bias = (float*)((char*)d_ws + (size_t)NCOLP * 1024 * 2);
  float* out = (float*)d_out;

  hipLaunchKernelGGL(ple_prep, dim3(NCOLP), dim3(256), 0, stream, Ws, bs, Wt, bt,
                     Wg, bg, Wpack, bias);
  hipLaunchKernelGGL(ple_main, dim3(BROWS / 64), dim3(256), 0, stream, x, Wpack,
                     bias, Wc, bc, Wv, bv, out);
}

// Round 11
// 88.557 us; speedup vs baseline: 1.2604x; 1.2604x over previous
//
#include <hip/hip_runtime.h>
#include <hip/hip_bf16.h>

typedef __attribute__((ext_vector_type(8))) short bf16x8;
typedef __attribute__((ext_vector_type(4))) float f32x4;

#define NCOLP 384                 // padded columns (352 real + 32 zero)
#define STEP_SHORTS (NCOLP * 32)  // 12288 shorts = 24576 B per 32-k step
#define STEP_BYTES 24576
#define SEG_BYTES 6144            // Wpack per-ablk segment: 384 cols * 8k * 2B
#define NSTEP 32
#define HSTEP 16
#define BROWS 65536

static __device__ __forceinline__ unsigned int bf16rne(float f) {
  unsigned int u = __float_as_uint(f);
  return (u + 0x7FFFu + ((u >> 16) & 1u)) >> 16;
}
static __device__ __forceinline__ unsigned int pack2(float a, float b) {
  return bf16rne(a) | (bf16rne(b) << 16);
}

// Wpack layout: [step][ablk(4)][col(384)][k%8] (bf16), 24576 B/step.
// Column map: [0,100) task0 (e*10+h), [100,200) task1, [200,300) shared,
// [300,340) gates (t*20+g), [340,384) zero pad.
__global__ void ple_prep(const float* __restrict__ Ws, const float* __restrict__ bs,
                         const float* __restrict__ Wt, const float* __restrict__ bt,
                         const float* __restrict__ Wg, const float* __restrict__ bg,
                         unsigned short* __restrict__ Wpack, float* __restrict__ bias) {
  const int n = blockIdx.x;  // 0..383
  const int tid = threadIdx.x;
  const float* src = nullptr;
  int stride = 0;
  float bval = 0.f;
  if (n < 200) {
    int t = n / 100, m = n % 100, e = m / 10, h = m % 10;
    src = Wt + (size_t)(t * 10 + e) * 10240 + h;
    stride = 10;
    bval = bt[(t * 10 + e) * 10 + h];
  } else if (n < 300) {
    int m = n - 200, e = m / 10, h = m % 10;
    src = Ws + (size_t)e * 10240 + h;
    stride = 10;
    bval = bs[e * 10 + h];
  } else if (n < 340) {
    int m = n - 300, t = m / 20, g = m % 20;
    src = Wg + (size_t)t * 20480 + g;
    stride = 20;
    bval = bg[t * 20 + g];
  }
  for (int j = 0; j < 4; j++) {
    int k = tid + j * 256;
    float v = src ? src[(size_t)k * stride] : 0.f;
    Wpack[(size_t)(k >> 5) * STEP_SHORTS + ((k >> 3) & 3) * (NCOLP * 8) + n * 8 +
          (k & 7)] = (unsigned short)bf16rne(v);
  }
  if (tid == 0 && n < 352) bias[n] = bval;
}

// Main: 256 threads = 4 waves, 64 rows/block, 1024 blocks, 2 blocks/CU.
// Phase-split: [stage half-K A tile: 32 coalesced global loads/thread ->
// cvt bf16 -> swizzled ds_write_b128] | barrier | [16 K-steps: ds_read_b128
// A-frags + register B from L2 Wpack + MFMA; no barriers, no HBM ops].
// The vmem FIFO inside compute holds ONLY B loads -> vmcnt waits drain
// nothing young. Stage burst of one resident block overlaps compute of the
// other. Each wave owns a 96-col slice: zero B duplication.
__global__ __launch_bounds__(256, 2) void ple_main(
    const float* __restrict__ x, const unsigned short* __restrict__ Wpack,
    const float* __restrict__ bias, const float* __restrict__ Wc,
    const float* __restrict__ bc, const float* __restrict__ Wv,
    const float* __restrict__ bv, float* __restrict__ out) {
  // A half-tile: 64 rows x 64 segs(16B bf16, XOR-swizzled) = 65536 B.
  // Epilogue z[32][357] (45.7 KB) aliases it after the final barrier.
  __shared__ __align__(16) char smem[65536];
  float* z = (float*)smem;

  const int tid = threadIdx.x;
  const int l = tid & 63, w = tid >> 6;  // wave w -> cols [w*96, w*96+96)
  const int arow = l & 15, ablk = l >> 4;
  const int rowbase = blockIdx.x * 64;

  const f32x4 fzero = {0.f, 0.f, 0.f, 0.f};
  f32x4 acc[4][6];
#pragma unroll
  for (int i = 0; i < 4; ++i)
#pragma unroll
    for (int j = 0; j < 6; ++j) acc[i][j] = fzero;

  // B fragment base (per-lane 16B from Wpack; k-order matches A frags).
  const char* bbase = (const char*)Wpack + ablk * SEG_BYTES +
                      (w * 96 + arow) * 16;
  bf16x8 bA[6], bB[6];  // double bank, static indexing only

  // Preload B(0).
#pragma unroll
  for (int nt = 0; nt < 6; nt++)
    bA[nt] = *(const bf16x8*)(bbase + nt * 256);

  for (int half = 0; half < 2; ++half) {
    // ---- stage phase: rows w, w+4, ..., w+60; lane l = seg l (8 k) ----
    {
      const char* xb = (const char*)x + (size_t)(rowbase + w) * 4096 +
                       (size_t)half * 2048 + l * 32;
#pragma unroll 4
      for (int j = 0; j < 16; j++) {
        const float4 f0 = *(const float4*)(xb + (size_t)j * 4 * 4096);
        const float4 f1 = *(const float4*)(xb + (size_t)j * 4 * 4096 + 16);
        const int row = w + j * 4;
        char* dst = smem + row * 1024 + ((l ^ (row & 7)) * 16);
        *(uint4*)dst = make_uint4(pack2(f0.x, f0.y), pack2(f0.z, f0.w),
                                  pack2(f1.x, f1.y), pack2(f1.z, f1.w));
      }
    }
    __syncthreads();  // A half-tile visible to all waves

    // ---- compute phase: 16 K-steps, barrier-free, LDS + B-regs only ----
    // STEP(ksl): issue B(kk+1) -> bn_, MFMA with bc_ (= B(kk)).
#define STEP(ksl, bc_, bn_)                                                    \
  {                                                                            \
    const int kk = half * HSTEP + (ksl);                                       \
    const int kn = (kk + 1 < NSTEP) ? kk + 1 : NSTEP - 1;                      \
    const char* bp = bbase + (size_t)kn * STEP_BYTES;                          \
    _Pragma("unroll") for (int nt = 0; nt < 6; nt++)                           \
        bn_[nt] = *(const bf16x8*)(bp + nt * 256);                             \
    _Pragma("unroll") for (int mf = 0; mf < 4; mf++) {                         \
      const bf16x8 av = *(const bf16x8*)(smem + (mf * 16 + arow) * 1024 +      \
                                         ((((ksl)*4 + ablk) ^ (arow & 7)) *    \
                                          16));                                \
      _Pragma("unroll") for (int nt = 0; nt < 6; nt++)                         \
          acc[mf][nt] = __builtin_amdgcn_mfma_f32_16x16x32_bf16(               \
              av, bc_[nt], acc[mf][nt], 0, 0, 0);                              \
    }                                                                          \
  }
#pragma unroll
    for (int kp = 0; kp < 8; kp++) {
      STEP(2 * kp, bA, bB)
      STEP(2 * kp + 1, bB, bA)
    }
#undef STEP
    __syncthreads();  // all reads done before next stage / epilogue reuse
  }

  // ---- epilogue: 2 phases of 32 rows. D layout: row=(l>>4)*4+reg, col=l&15.
#pragma unroll
  for (int p = 0; p < 2; p++) {
    __syncthreads();
#pragma unroll
    for (int q = 0; q < 2; q++) {
      const int mf = p * 2 + q;
#pragma unroll
      for (int nt = 0; nt < 6; nt++) {
        if (w == 3 && nt >= 4) continue;  // cols >= 352 are zero pad
#pragma unroll
        for (int r = 0; r < 4; r++)
          z[(q * 16 + ablk * 4 + r) * 357 + w * 96 + nt * 16 + arow] =
              acc[mf][nt][r];
      }
    }
    __syncthreads();
    if (tid < 64) {
      const int t = tid >> 5, r = tid & 31;
      const float* zr = &z[r * 357];
      float gl[20], m = -1e30f;
#pragma unroll
      for (int u = 0; u < 20; u++) {
        gl[u] = zr[300 + t * 20 + u] + bias[300 + t * 20 + u];
        m = fmaxf(m, gl[u]);
      }
      float pr[20], s = 0.f;
#pragma unroll
      for (int u = 0; u < 20; u++) {
        pr[u] = __expf(gl[u] - m);
        s += pr[u];
      }
      const float inv = 1.f / s;
      const float* Wl = t ? Wv : Wc;
      float wl[10];
#pragma unroll
      for (int h = 0; h < 10; h++) wl[h] = Wl[h];
      float accum = 0.f;
#pragma unroll
      for (int u = 0; u < 10; u++) {
        float d = 0.f;
#pragma unroll
        for (int h = 0; h < 10; h++) {
          int c = t * 100 + u * 10 + h;
          d += fmaxf(zr[c] + bias[c], 0.f) * wl[h];
        }
        accum += pr[u] * d;
      }
#pragma unroll
      for (int u = 0; u < 10; u++) {
        float d = 0.f;
#pragma unroll
        for (int h = 0; h < 10; h++) {
          int c = 200 + u * 10 + h;
          d += fmaxf(zr[c] + bias[c], 0.f) * wl[h];
        }
        accum += pr[10 + u] * d;
      }
      float logit = (t ? bv[0] : bc[0]) + accum * inv;
      out[(size_t)t * BROWS + rowbase + p * 32 + r] =
          1.f / (1.f + __expf(-logit));
    }
  }
}

extern "C" void kernel_launch(void* const* d_in, const int* in_sizes, int n_in,
                              void* d_out, int out_size, void* d_ws, size_t ws_size,
                              hipStream_t stream) {
  const float* x = (const float*)d_in[0];
  const float* Ws = (const float*)d_in[3];
  const float* bs = (const float*)d_in[4];
  const float* Wt = (const float*)d_in[5];
  const float* bt = (const float*)d_in[6];
  const float* Wg = (const float*)d_in[7];
  const float* bg = (const float*)d_in[8];
  const float* Wc = (const float*)d_in[9];
  const float* bc = (const float*)d_in[10];
  const float* Wv = (const float*)d_in[11];
  const float* bv = (const float*)d_in[12];
  unsigned short* Wpack = (unsigned short*)d_ws;
  float* bias = (float*)((char*)d_ws + (size_t)NCOLP * 1024 * 2);
  float* out = (float*)d_out;

  hipLaunchKernelGGL(ple_prep, dim3(NCOLP), dim3(256), 0, stream, Ws, bs, Wt, bt,
                     Wg, bg, Wpack, bias);
  hipLaunchKernelGGL(ple_main, dim3(BROWS / 64), dim3(256), 0, stream, x, Wpack,
                     bias, Wc, bc, Wv, bv, out);
}